// Round 10
// baseline (44.621 us; speedup 1.0000x reference)
//
#include <hip/hip_runtime.h>
#include <hip/hip_fp16.h>
#include <math.h>

#define IMG   256
#define NANG  180
#define NDET  363
#define PAD   3
#define PS    264                    // padded stride (texels)
#define PSZ   (PS * PS)              // texels per layout
#define LR    52                     // staged LDS rows
#define LC    52                     // staged LDS cols (= pitch, texels)
#define TEX_BYTES ((size_t)2 * PSZ * 8)          // 2 layouts of uint2 texels
#define PP_BYTES  ((size_t)NANG * 8 * IMG * 16)  // proj_part float4 (8 i-tiles)
#define WS_NEED   (TEX_BYTES + PP_BYTES)

__device__ __forceinline__ __half2 u2h2(unsigned u) {
    return *reinterpret_cast<__half2*>(&u);
}
__device__ __forceinline__ unsigned h22u(__half2 h) {
    return *reinterpret_cast<unsigned*>(&h);
}

// ---- prep: fp16x4 batch-interleaved zero-padded normal + transposed layouts ----
__global__ __launch_bounds__(1024) void prep_kernel(const float* __restrict__ x,
                                                    uint2* __restrict__ ws) {
    __shared__ uint2 tile[32][33];
    const int tx = threadIdx.x, ty = threadIdx.y;
    const int px = blockIdx.x * 32 + tx;   // padded x
    const int py = blockIdx.y * 32 + ty;   // padded y
    const int ix = px - PAD, iy = py - PAD;

    uint2 t = make_uint2(0u, 0u);
    if ((unsigned)ix < IMG && (unsigned)iy < IMG) {
        const size_t o = (size_t)iy * IMG + ix;
        t.x = h22u(__floats2half2_rn(x[o],                 x[o + IMG * IMG]));
        t.y = h22u(__floats2half2_rn(x[o + 2 * IMG * IMG], x[o + 3 * IMG * IMG]));
    }
    if (px < PS && py < PS) ws[(size_t)py * PS + px] = t;          // N[py][px]
    tile[ty][tx] = t;
    __syncthreads();
    const int opx = blockIdx.y * 32 + tx;  // fast dim = original py
    const int opy = blockIdx.x * 32 + ty;  // slow dim = original px
    if (opx < PS && opy < PS)
        ws[(size_t)PSZ + (size_t)opy * PS + opx] = tile[tx][ty];   // T[u][v]=img[v][u]
}

// ---- main: grid (angle, it*8+jt); 128 thr = 2 waves; tile = 32 i x 32 j.
//      Stage the tile's image bbox (<=52x52 texels) into LDS, tap from LDS. ----
__global__ __launch_bounds__(128) void radon_main(const uint2* __restrict__ ws,
                                                  float4* __restrict__ proj_part) {
    const int a   = blockIdx.x;
    const int it  = blockIdx.y >> 3;       // i-tile 0..7
    const int jt  = blockIdx.y & 7;        // j-tile 0..7
    const int i0  = it * 32, j0 = jt * 32;
    const int tid = threadIdx.x;
    const int lane = tid & 63;
    const int w    = tid >> 6;             // wave 0..1 -> j sub-tile
    const int jj   = lane & 15;
    const int ii4  = lane >> 4;            // 0..3 i-subgroup
    const int j    = j0 + w * 16 + jj;

    const float ang = (float)a * 0.017453292519943295f;
    const float cs = cosf(ang);            // cos(-ang)
    const float sn = -sinf(ang);           // sin(-ang)

    // per-thread sample line (identical arithmetic to r6)
    const float xcj = -1.0f + (2.0f / 255.0f) * (float)j;
    const float fx0 = 127.5f * (xcj * cs + sn + 1.0f);
    const float dfx = -sn;
    const float fy0 = 127.5f * (xcj * sn - cs + 1.0f);
    const float dfy = cs;

    const bool swp = fabsf(sn) > fabsf(cs);
    const float rc0 = swp ? fx0 : fy0;  const float drow = swp ? dfx : dfy;
    const float cc0 = swp ? fy0 : fx0;  const float dcol = swp ? dfy : dfx;
    const uint2* __restrict__ gtex = ws + (swp ? PSZ : 0);

    // ---- block-uniform bbox of the tile in (swapped) image coords ----
    // rc(i,j) = rb + j*rjs + i*drow ; cc(i,j) = cb + j*cjs + i*dcol
    const float fxb = 127.5f * (sn - cs + 1.0f);   // fx0 at j=0
    const float fyb = 127.5f * (-sn - cs + 1.0f);  // fy0 at j=0
    const float rb  = swp ? fxb : fyb;
    const float cb  = swp ? fyb : fxb;
    const float rjs = swp ? cs : sn;               // d(rc)/dj
    const float cjs = swp ? sn : cs;               // d(cc)/dj

    const float jr0 = (float)j0 * rjs,  jr1 = (float)(j0 + 31) * rjs;
    const float ir0 = (float)i0 * drow, ir1 = (float)(i0 + 31) * drow;
    const float jc0 = (float)j0 * cjs,  jc1 = (float)(j0 + 31) * cjs;
    const float ic0 = (float)i0 * dcol, ic1 = (float)(i0 + 31) * dcol;
    const float rmin_f = rb + fminf(jr0, jr1) + fminf(ir0, ir1);
    const float cmin_f = cb + fminf(jc0, jc1) + fminf(ic0, ic1);

    int rmin_p = (int)floorf(rmin_f) + PAD - 2;
    rmin_p = min(max(rmin_p, 0), PS - LR);
    int cmin_p = (int)floorf(cmin_f) + PAD - 2;
    cmin_p = (min(max(cmin_p, 0), PS - LC)) & ~1;   // even for uint4 staging

    // ---- stage bbox into LDS (coalesced uint4 rows) ----
    __shared__ __align__(16) uint2 s_tile[LR * LC];
    {
        const uint4* __restrict__ g4 =
            reinterpret_cast<const uint4*>(gtex + (size_t)rmin_p * PS + cmin_p);
        uint4* s4 = reinterpret_cast<uint4*>(s_tile);
        #pragma unroll
        for (int t = 0; t < 11; ++t) {
            const int idx = tid + t * 128;
            if (idx < LR * (LC / 2)) {
                const int r = idx / (LC / 2);
                const int c = idx - r * (LC / 2);
                s4[idx] = g4[(size_t)r * (PS / 2) + c];
            }
        }
    }
    __syncthreads();

    // ---- valid i-window (global bounds; slop lands in zero pad / staged margin) ----
    float lo = 0.0f, hi = 255.0f;
    if (fabsf(drow) > 1e-5f) {
        const float t1 = (-1.5f - rc0) / drow, t2 = (256.5f - rc0) / drow;
        lo = fmaxf(lo, fminf(t1, t2));
        hi = fminf(hi, fmaxf(t1, t2));
    } else if (rc0 < -1.5f || rc0 > 256.5f) { lo = 1.0f; hi = 0.0f; }
    if (fabsf(dcol) > 1e-5f) {
        const float t1 = (-1.5f - cc0) / dcol, t2 = (256.5f - cc0) / dcol;
        lo = fmaxf(lo, fminf(t1, t2));
        hi = fminf(hi, fmaxf(t1, t2));
    } else if (cc0 < -1.5f || cc0 > 256.5f) { lo = 1.0f; hi = 0.0f; }

    const int ilo_t = max((int)floorf(lo), i0);
    const int ihi_t = min(min((int)ceilf(hi), i0 + 31), 255);
    const int d0 = ilo_t - i0 - ii4;
    const int d1 = ihi_t - i0 - ii4;
    const int klo = max(0, (d0 + 3) >> 2);
    const int khi = min(7, d1 >> 2);

    // LDS-relative base: texel (r,c) -> s_tile[(r+PAD-rmin_p)*LC + (c+PAD-cmin_p)]
    const int lbase = (PAD - rmin_p) * LC + (PAD - cmin_p);

    float4 sum = make_float4(0.f, 0.f, 0.f, 0.f);
    #pragma unroll
    for (int k = klo; k <= khi; ++k) {
        const int i = i0 + ii4 + (k << 2);
        const float rc = fmaf((float)i, drow, rc0);
        const float cc = fmaf((float)i, dcol, cc0);
        const float rf = floorf(rc);
        const float cf = floorf(cc);
        const float wr = rc - rf;
        const float wc = cc - cf;
        const int sidx = (int)rf * LC + (int)cf + lbase;

        const uint2 t00 = s_tile[sidx];
        const uint2 t01 = s_tile[sidx + 1];
        const uint2 t10 = s_tile[sidx + LC];
        const uint2 t11 = s_tile[sidx + LC + 1];

        const __half2 wc2 = __float2half2_rn(wc);
        const __half2 wr2 = __float2half2_rn(wr);

        const __half2 v00a = u2h2(t00.x), v00b = u2h2(t00.y);
        const __half2 v01a = u2h2(t01.x), v01b = u2h2(t01.y);
        const __half2 v10a = u2h2(t10.x), v10b = u2h2(t10.y);
        const __half2 v11a = u2h2(t11.x), v11b = u2h2(t11.y);

        const __half2 topa = __hfma2(wc2, __hsub2(v01a, v00a), v00a);
        const __half2 topb = __hfma2(wc2, __hsub2(v01b, v00b), v00b);
        const __half2 bota = __hfma2(wc2, __hsub2(v11a, v10a), v10a);
        const __half2 botb = __hfma2(wc2, __hsub2(v11b, v10b), v10b);
        const __half2 ra = __hfma2(wr2, __hsub2(bota, topa), topa);
        const __half2 rb2 = __hfma2(wr2, __hsub2(botb, topb), topb);

        sum.x += __low2float(ra);
        sum.y += __high2float(ra);
        sum.z += __low2float(rb2);
        sum.w += __high2float(rb2);
    }

    // butterfly-reduce across the 4 i-subgroups
    sum.x += __shfl_xor(sum.x, 16, 64);
    sum.y += __shfl_xor(sum.y, 16, 64);
    sum.z += __shfl_xor(sum.z, 16, 64);
    sum.w += __shfl_xor(sum.w, 16, 64);
    sum.x += __shfl_xor(sum.x, 32, 64);
    sum.y += __shfl_xor(sum.y, 32, 64);
    sum.z += __shfl_xor(sum.z, 32, 64);
    sum.w += __shfl_xor(sum.w, 32, 64);

    if (ii4 == 0) {
        proj_part[(size_t)(a * 8 + it) * IMG + j] = sum;
    }
}

// ---- detect: per angle, sum 8 i-tiles, resample detectors, write 4 batches ----
__global__ __launch_bounds__(384) void detect_kernel(const float4* __restrict__ proj_part,
                                                     float* __restrict__ out) {
    const int a = blockIdx.x;
    const int t = threadIdx.x;
    __shared__ float4 proj[IMG];
    if (t < IMG) {
        float4 s = proj_part[(size_t)(a * 8 + 0) * IMG + t];
        #pragma unroll
        for (int q = 1; q < 8; ++q) {
            const float4 p = proj_part[(size_t)(a * 8 + q) * IMG + t];
            s.x += p.x; s.y += p.y; s.z += p.z; s.w += p.w;
        }
        proj[t] = s;
    }
    __syncthreads();
    if (t < NDET) {
        const float pos = (float)t * (255.0f / 362.0f);
        const float fp = floorf(pos);
        const int p0 = (int)fp;
        const int p1 = min(p0 + 1, IMG - 1);
        const float w = pos - fp;
        const float4 lo = proj[p0], hi = proj[p1];
        const size_t o = (size_t)a * NDET + t;
        out[o]                   = fmaf(w, hi.x - lo.x, lo.x);
        out[o + 1 * NANG * NDET] = fmaf(w, hi.y - lo.y, lo.y);
        out[o + 2 * NANG * NDET] = fmaf(w, hi.z - lo.z, lo.z);
        out[o + 3 * NANG * NDET] = fmaf(w, hi.w - lo.w, lo.w);
    }
}

// ---- last-resort fallback (no workspace) ----
__global__ __launch_bounds__(256) void radon_fallback(const float* __restrict__ x,
                                                      float* __restrict__ out) {
    const int blk = blockIdx.x;
    const int a = blk >> 2;
    const int b = blk & 3;
    const int j = threadIdx.x;
    const float* __restrict__ img = x + (size_t)b * (IMG * IMG);
    const float ang = (float)a * 0.017453292519943295f;
    const float cs = cosf(ang);
    const float sn = -sinf(ang);
    const float xcj = -1.0f + (2.0f / 255.0f) * (float)j;
    const float gx0 = xcj * cs;
    const float gy0 = xcj * sn;
    float sum = 0.0f;
    for (int i = 0; i < IMG; ++i) {
        const float yci = -1.0f + (2.0f / 255.0f) * (float)i;
        const float fx = (gx0 - yci * sn + 1.0f) * 127.5f;
        const float fy = (gy0 + yci * cs + 1.0f) * 127.5f;
        const float flx = floorf(fx), fly = floorf(fy);
        const int x0 = (int)flx, y0 = (int)fly;
        const float wx = fx - flx, wy = fy - fly;
        const bool vx0 = ((unsigned)x0 < IMG), vx1 = ((unsigned)(x0 + 1) < IMG);
        const bool vy0 = ((unsigned)y0 < IMG), vy1 = ((unsigned)(y0 + 1) < IMG);
        if (!((vx0 | vx1) & (vy0 | vy1))) continue;
        const int xc0 = min(max(x0, 0), IMG - 1), xc1 = min(max(x0 + 1, 0), IMG - 1);
        const int yc0 = min(max(y0, 0), IMG - 1), yc1 = min(max(y0 + 1, 0), IMG - 1);
        const float* r0 = img + yc0 * IMG;
        const float* r1 = img + yc1 * IMG;
        const float v00 = (vy0 && vx0) ? r0[xc0] : 0.0f;
        const float v01 = (vy0 && vx1) ? r0[xc1] : 0.0f;
        const float v10 = (vy1 && vx0) ? r1[xc0] : 0.0f;
        const float v11 = (vy1 && vx1) ? r1[xc1] : 0.0f;
        sum += (1.0f - wy) * ((1.0f - wx) * v00 + wx * v01)
             +         wy  * ((1.0f - wx) * v10 + wx * v11);
    }
    __shared__ float proj[IMG];
    proj[j] = sum;
    __syncthreads();
    for (int d = j; d < NDET; d += 256) {
        const float pos = (float)d * (255.0f / 362.0f);
        const float fp = floorf(pos);
        const int p0 = (int)fp;
        const int p1 = min(p0 + 1, IMG - 1);
        const float w = pos - fp;
        out[(size_t)b * (NANG * NDET) + a * NDET + d] = proj[p0] * (1.0f - w) + proj[p1] * w;
    }
}

extern "C" void kernel_launch(void* const* d_in, const int* in_sizes, int n_in,
                              void* d_out, int out_size, void* d_ws, size_t ws_size,
                              hipStream_t stream) {
    const float* x = (const float*)d_in[0];
    float* out = (float*)d_out;
    (void)in_sizes; (void)n_in; (void)out_size;

    if (ws_size < WS_NEED) {
        radon_fallback<<<dim3(NANG * 4), dim3(256), 0, stream>>>(x, out);
        return;
    }

    uint2* tex = (uint2*)d_ws;
    float4* proj_part = (float4*)((char*)d_ws + TEX_BYTES);

    prep_kernel<<<dim3(9, 9), dim3(32, 32), 0, stream>>>(x, tex);
    radon_main<<<dim3(NANG, 64), dim3(128), 0, stream>>>(tex, proj_part);
    detect_kernel<<<dim3(NANG), dim3(384), 0, stream>>>(proj_part, out);
}

// Round 11
// 30.250 us; speedup vs baseline: 1.4751x; 1.4751x over previous
//
#include <hip/hip_runtime.h>
#include <hip/hip_fp16.h>
#include <math.h>

#define IMG   256
#define NANG  180
#define NDET  363
#define PAD   3
#define PS    264                    // padded stride (texels)
#define PSZ   (PS * PS)              // texels per layout
#define TEX_BYTES ((size_t)2 * PSZ * 8)          // 2 layouts of uint2 texels
#define PP_BYTES  ((size_t)NANG * 2 * IMG * 16)  // proj_part float4 (2 i-halves)
#define WS_NEED   (TEX_BYTES + PP_BYTES)

__device__ __forceinline__ __half2 u2h2(unsigned u) {
    return *reinterpret_cast<__half2*>(&u);
}
__device__ __forceinline__ unsigned h22u(__half2 h) {
    return *reinterpret_cast<unsigned*>(&h);
}

// ---- prep: fp16x4 batch-interleaved zero-padded normal + transposed layouts ----
__global__ __launch_bounds__(1024) void prep_kernel(const float* __restrict__ x,
                                                    uint2* __restrict__ ws) {
    __shared__ uint2 tile[32][33];
    const int tx = threadIdx.x, ty = threadIdx.y;
    const int px = blockIdx.x * 32 + tx;   // padded x
    const int py = blockIdx.y * 32 + ty;   // padded y
    const int ix = px - PAD, iy = py - PAD;

    uint2 t = make_uint2(0u, 0u);
    if ((unsigned)ix < IMG && (unsigned)iy < IMG) {
        const size_t o = (size_t)iy * IMG + ix;
        t.x = h22u(__floats2half2_rn(x[o],                 x[o + IMG * IMG]));
        t.y = h22u(__floats2half2_rn(x[o + 2 * IMG * IMG], x[o + 3 * IMG * IMG]));
    }
    if (px < PS && py < PS) ws[(size_t)py * PS + px] = t;          // N[py][px]
    tile[ty][tx] = t;
    __syncthreads();
    const int opx = blockIdx.y * 32 + tx;  // fast dim = original py
    const int opy = blockIdx.x * 32 + ty;  // slow dim = original px
    if (opx < PS && opy < PS)
        ws[(size_t)PSZ + (size_t)opy * PS + opx] = tile[tx][ty];   // T[u][v]=img[v][u]
}

// ---- main: grid (angle, ih*4+jq); 256 thr = 4 waves; wave = 16 j x 4 i-lanes ----
__global__ __launch_bounds__(256) void radon_main(const uint2* __restrict__ ws,
                                                  float4* __restrict__ proj_part) {
    const int a    = blockIdx.x;
    const int ih   = blockIdx.y >> 2;      // i-half: 0..1 (128 i's each)
    const int jq   = blockIdx.y & 3;       // j-quarter: 0..3 (64 j's each)
    const int tid  = threadIdx.x;
    const int lane = tid & 63;
    const int wv   = tid >> 6;             // wave 0..3 -> j-tile within quarter
    const int jj   = lane & 15;
    const int ii4  = lane >> 4;            // 0..3 i-subgroup
    const int j    = jq * 64 + wv * 16 + jj;

    const float ang = (float)a * 0.017453292519943295f;
    const float cs = cosf(ang);            // cos(-ang)
    const float sn = -sinf(ang);           // sin(-ang)

    const float xcj = -1.0f + (2.0f / 255.0f) * (float)j;
    const float fx0 = 127.5f * (xcj * cs + sn + 1.0f);
    const float dfx = -sn;
    const float fy0 = 127.5f * (xcj * sn - cs + 1.0f);
    const float dfy = cs;

    // layout so the lane-fast (j) coordinate strides the stored-row direction
    const bool swp = fabsf(sn) > fabsf(cs);
    const float rc0 = swp ? fx0 : fy0;  const float drow = swp ? dfx : dfy;
    const float cc0 = swp ? fy0 : fx0;  const float dcol = swp ? dfy : dfx;
    const uint2* __restrict__ base = ws + (swp ? PSZ : 0);

    // valid i-window (conservative; slop lands in the zero pad)
    float lo = 0.0f, hi = 255.0f;
    if (fabsf(drow) > 1e-5f) {
        const float t1 = (-1.5f - rc0) / drow, t2 = (256.5f - rc0) / drow;
        lo = fmaxf(lo, fminf(t1, t2));
        hi = fminf(hi, fmaxf(t1, t2));
    } else if (rc0 < -1.5f || rc0 > 256.5f) { lo = 1.0f; hi = 0.0f; }
    if (fabsf(dcol) > 1e-5f) {
        const float t1 = (-1.5f - cc0) / dcol, t2 = (256.5f - cc0) / dcol;
        lo = fmaxf(lo, fminf(t1, t2));
        hi = fminf(hi, fmaxf(t1, t2));
    } else if (cc0 < -1.5f || cc0 > 256.5f) { lo = 1.0f; hi = 0.0f; }

    const int ibase = ih * 128;
    const int ilo_t = max((int)floorf(lo), ibase);
    int ihi_t = min((int)ceilf(hi), ibase + 127);
    ihi_t = min(ihi_t, 255);
    const int d0 = ilo_t - ibase - ii4;
    const int d1 = ihi_t - ibase - ii4;
    const int klo = max(0, (d0 + 3) >> 2);
    const int khi = min(31, d1 >> 2);

    float4 sum = make_float4(0.f, 0.f, 0.f, 0.f);
    #pragma unroll 4
    for (int k = klo; k <= khi; ++k) {
        const int i = ibase + ii4 + (k << 2);
        const float rc = fmaf((float)i, drow, rc0);
        const float cc = fmaf((float)i, dcol, cc0);
        const float rf = floorf(rc);
        const float cf = floorf(cc);
        const float wr = rc - rf;
        const float wc = cc - cf;
        const int idx = (int)fmaf(rf, (float)PS, cf) + (PAD * PS + PAD);

        // one 16B load = both horizontal taps (4 batches each), per row
        const uint4 tr = *reinterpret_cast<const uint4*>(base + idx);       // row r0
        const uint4 br = *reinterpret_cast<const uint4*>(base + idx + PS);  // row r0+1

        const __half2 wc2 = __float2half2_rn(wc);
        const __half2 wr2 = __float2half2_rn(wr);

        const __half2 v00a = u2h2(tr.x), v00b = u2h2(tr.y);
        const __half2 v01a = u2h2(tr.z), v01b = u2h2(tr.w);
        const __half2 v10a = u2h2(br.x), v10b = u2h2(br.y);
        const __half2 v11a = u2h2(br.z), v11b = u2h2(br.w);

        const __half2 topa = __hfma2(wc2, __hsub2(v01a, v00a), v00a);
        const __half2 topb = __hfma2(wc2, __hsub2(v01b, v00b), v00b);
        const __half2 bota = __hfma2(wc2, __hsub2(v11a, v10a), v10a);
        const __half2 botb = __hfma2(wc2, __hsub2(v11b, v10b), v10b);
        const __half2 ra = __hfma2(wr2, __hsub2(bota, topa), topa);
        const __half2 rb = __hfma2(wr2, __hsub2(botb, topb), topb);

        sum.x += __low2float(ra);
        sum.y += __high2float(ra);
        sum.z += __low2float(rb);
        sum.w += __high2float(rb);
    }

    // butterfly-reduce across the 4 i-subgroups
    sum.x += __shfl_xor(sum.x, 16, 64);
    sum.y += __shfl_xor(sum.y, 16, 64);
    sum.z += __shfl_xor(sum.z, 16, 64);
    sum.w += __shfl_xor(sum.w, 16, 64);
    sum.x += __shfl_xor(sum.x, 32, 64);
    sum.y += __shfl_xor(sum.y, 32, 64);
    sum.z += __shfl_xor(sum.z, 32, 64);
    sum.w += __shfl_xor(sum.w, 32, 64);

    if (ii4 == 0) {
        proj_part[(size_t)(a * 2 + ih) * IMG + j] = sum;
    }
}

// ---- detect: per angle, sum 2 i-halves, resample detectors, write 4 batches ----
__global__ __launch_bounds__(384) void detect_kernel(const float4* __restrict__ proj_part,
                                                     float* __restrict__ out) {
    const int a = blockIdx.x;
    const int t = threadIdx.x;
    __shared__ float4 proj[IMG];
    if (t < IMG) {
        const float4 p0 = proj_part[(size_t)(a * 2 + 0) * IMG + t];
        const float4 p1 = proj_part[(size_t)(a * 2 + 1) * IMG + t];
        proj[t] = make_float4(p0.x + p1.x, p0.y + p1.y, p0.z + p1.z, p0.w + p1.w);
    }
    __syncthreads();
    if (t < NDET) {
        const float pos = (float)t * (255.0f / 362.0f);
        const float fp = floorf(pos);
        const int p0 = (int)fp;
        const int p1 = min(p0 + 1, IMG - 1);
        const float w = pos - fp;
        const float4 lo = proj[p0], hi = proj[p1];
        const size_t o = (size_t)a * NDET + t;
        out[o]                   = fmaf(w, hi.x - lo.x, lo.x);
        out[o + 1 * NANG * NDET] = fmaf(w, hi.y - lo.y, lo.y);
        out[o + 2 * NANG * NDET] = fmaf(w, hi.z - lo.z, lo.z);
        out[o + 3 * NANG * NDET] = fmaf(w, hi.w - lo.w, lo.w);
    }
}

// ---- last-resort fallback (no workspace) ----
__global__ __launch_bounds__(256) void radon_fallback(const float* __restrict__ x,
                                                      float* __restrict__ out) {
    const int blk = blockIdx.x;
    const int a = blk >> 2;
    const int b = blk & 3;
    const int j = threadIdx.x;
    const float* __restrict__ img = x + (size_t)b * (IMG * IMG);
    const float ang = (float)a * 0.017453292519943295f;
    const float cs = cosf(ang);
    const float sn = -sinf(ang);
    const float xcj = -1.0f + (2.0f / 255.0f) * (float)j;
    const float gx0 = xcj * cs;
    const float gy0 = xcj * sn;
    float sum = 0.0f;
    for (int i = 0; i < IMG; ++i) {
        const float yci = -1.0f + (2.0f / 255.0f) * (float)i;
        const float fx = (gx0 - yci * sn + 1.0f) * 127.5f;
        const float fy = (gy0 + yci * cs + 1.0f) * 127.5f;
        const float flx = floorf(fx), fly = floorf(fy);
        const int x0 = (int)flx, y0 = (int)fly;
        const float wx = fx - flx, wy = fy - fly;
        const bool vx0 = ((unsigned)x0 < IMG), vx1 = ((unsigned)(x0 + 1) < IMG);
        const bool vy0 = ((unsigned)y0 < IMG), vy1 = ((unsigned)(y0 + 1) < IMG);
        if (!((vx0 | vx1) & (vy0 | vy1))) continue;
        const int xc0 = min(max(x0, 0), IMG - 1), xc1 = min(max(x0 + 1, 0), IMG - 1);
        const int yc0 = min(max(y0, 0), IMG - 1), yc1 = min(max(y0 + 1, 0), IMG - 1);
        const float* r0 = img + yc0 * IMG;
        const float* r1 = img + yc1 * IMG;
        const float v00 = (vy0 && vx0) ? r0[xc0] : 0.0f;
        const float v01 = (vy0 && vx1) ? r0[xc1] : 0.0f;
        const float v10 = (vy1 && vx0) ? r1[xc0] : 0.0f;
        const float v11 = (vy1 && vx1) ? r1[xc1] : 0.0f;
        sum += (1.0f - wy) * ((1.0f - wx) * v00 + wx * v01)
             +         wy  * ((1.0f - wx) * v10 + wx * v11);
    }
    __shared__ float proj[IMG];
    proj[j] = sum;
    __syncthreads();
    for (int d = j; d < NDET; d += 256) {
        const float pos = (float)d * (255.0f / 362.0f);
        const float fp = floorf(pos);
        const int p0 = (int)fp;
        const int p1 = min(p0 + 1, IMG - 1);
        const float w = pos - fp;
        out[(size_t)b * (NANG * NDET) + a * NDET + d] = proj[p0] * (1.0f - w) + proj[p1] * w;
    }
}

extern "C" void kernel_launch(void* const* d_in, const int* in_sizes, int n_in,
                              void* d_out, int out_size, void* d_ws, size_t ws_size,
                              hipStream_t stream) {
    const float* x = (const float*)d_in[0];
    float* out = (float*)d_out;
    (void)in_sizes; (void)n_in; (void)out_size;

    if (ws_size < WS_NEED) {
        radon_fallback<<<dim3(NANG * 4), dim3(256), 0, stream>>>(x, out);
        return;
    }

    uint2* tex = (uint2*)d_ws;
    float4* proj_part = (float4*)((char*)d_ws + TEX_BYTES);

    prep_kernel<<<dim3(9, 9), dim3(32, 32), 0, stream>>>(x, tex);
    radon_main<<<dim3(NANG, 8), dim3(256), 0, stream>>>(tex, proj_part);
    detect_kernel<<<dim3(NANG), dim3(384), 0, stream>>>(proj_part, out);
}